// Round 6
// baseline (311.508 us; speedup 1.0000x reference)
//
#include <hip/hip_runtime.h>
#include <math.h>

#define NEG_SLOPE 0.2f
#define NBUK_MAX 512    // LDS capacity for bucket counters (buckets of 256 dsts; NBUK=391, must be <=512)

typedef float v4f __attribute__((ext_vector_type(4)));
typedef _Float16 h4v __attribute__((ext_vector_type(4)));   // 8B: 4 packed fp16 features

// Per-node hot data (per-edge random gathers, must stay L2-resident, total 3.6MB):
//   hT:   N x 16 f16 (32B rows)  - feature gather
//   asrc: N x f32               - alpha_src gather
// Per-dst data (read once per dst): meta int4 {asrc(f32), adst(f32), r0, r1}
// Streams (edst/esrc/tmp/csr_src/x) use NT *loads* only; scattered stores stay cached
// (NT scattered stores = ~16x write amplification, measured round 4: 85MB for 6.4MB csr).
// GAT inner loop is 2-deep software-pipelined: H-gathers issued one chunk before use
// (round 5 measured latency-bound: VALUBusy 8.5%, HBM 12%, both far from any roof).

// ---------------- K_A: histB (blocks 0..B2) UNION argmax (rest) ----------------
template <int B2>
__global__ void __launch_bounds__(1024)
k_histarg(const float* __restrict__ x, const int* __restrict__ edst, int E,
          int* __restrict__ histT, int NBUK, int* __restrict__ idx, int N, int V) {
    __shared__ int sh[NBUK_MAX];
    int t = threadIdx.x;
    if ((int)blockIdx.x < B2) {
        int b = blockIdx.x;
        for (int k = t; k < NBUK; k += 1024) sh[k] = 0;
        __syncthreads();
        long long ebeg = (long long)b * E / B2, eend = (long long)(b + 1) * E / B2;
        for (long long i = ebeg + t; i < eend; i += 1024)
            atomicAdd(&sh[__builtin_nontemporal_load(&edst[i]) >> 8], 1);
        __syncthreads();
        for (int k = t; k < NBUK; k += 1024) histT[(long long)k * B2 + b] = sh[k];
    } else {
        int node = ((int)blockIdx.x - B2) * 32 + (t >> 5);
        int lane = t & 31;
        if (node >= N) return;
        const v4f* row = (const v4f*)(x + (long long)node * V);
        float bv = -INFINITY;
        int bi = 0x7fffffff;
        int nq = V >> 2;
        for (int q = lane; q < nq; q += 32) {
            v4f v = __builtin_nontemporal_load(&row[q]);
            int base = q << 2;
            if (v.x > bv || (v.x == bv && base     < bi)) { bv = v.x; bi = base;     }
            if (v.y > bv || (v.y == bv && base + 1 < bi)) { bv = v.y; bi = base + 1; }
            if (v.z > bv || (v.z == bv && base + 2 < bi)) { bv = v.z; bi = base + 2; }
            if (v.w > bv || (v.w == bv && base + 3 < bi)) { bv = v.w; bi = base + 3; }
        }
        for (int off = 16; off > 0; off >>= 1) {
            float ov = __shfl_down(bv, off, 32);
            int   oi = __shfl_down(bi, off, 32);
            if (ov > bv || (ov == bv && oi < bi)) { bv = ov; bi = oi; }
        }
        if (lane == 0) idx[node] = bi;
    }
}

// ---------------- K_B: scan1 (blocks 0..NB_SCAN) UNION layer-1 transform (rest) ----------------
// Transform writes hT rows, asrc, and meta.xy = {asrc,adst}. r0/r1 (meta.zw) filled by binB.
template <int FIN, int FOUT>
__global__ void __launch_bounds__(256)
k_scan_tr(const int* __restrict__ vals, int* __restrict__ excl, int* __restrict__ bsums, int M,
          const float* __restrict__ emb, const int* __restrict__ idx,
          const float* __restrict__ W, const float* __restrict__ a_src,
          const float* __restrict__ a_dst, _Float16* __restrict__ hT,
          float* __restrict__ asrc, int4* __restrict__ meta,
          int N, int NB_SCAN) {
    __shared__ int s[256];
    __shared__ float sW[FIN * FOUT];
    __shared__ float sa[FOUT], sd[FOUT];
    int t = threadIdx.x;
    if ((int)blockIdx.x < NB_SCAN) {
        int i = blockIdx.x * 256 + t;
        int v = (i < M) ? vals[i] : 0;
        s[t] = v;
        __syncthreads();
        for (int off = 1; off < 256; off <<= 1) {
            int a = (t >= off) ? s[t - off] : 0;
            __syncthreads();
            s[t] += a;
            __syncthreads();
        }
        if (i < M) excl[i] = s[t] - v;
        if (t == 255) bsums[blockIdx.x] = s[255];   // raw chunk sums (scanned locally by consumers)
    } else {
        for (int i = t; i < FIN * FOUT; i += 256) sW[i] = W[i];
        if (t < FOUT) { sa[t] = a_src[t]; sd[t] = a_dst[t]; }
        __syncthreads();
        int n = ((int)blockIdx.x - NB_SCAN) * 256 + t;
        if (n >= N) return;
        float acc[FOUT];
#pragma unroll
        for (int f = 0; f < FOUT; f++) acc[f] = 0.f;
        const float* hr = emb + (long long)idx[n] * FIN;
        for (int k = 0; k < FIN; k++) {
            float v = hr[k];
#pragma unroll
            for (int f = 0; f < FOUT; f++) acc[f] += v * sW[k * FOUT + f];
        }
        float s1 = 0.f, s2 = 0.f;
        _Float16 hh[16];
#pragma unroll
        for (int f = 0; f < 16; f++) hh[f] = (_Float16)0.f;
#pragma unroll
        for (int f = 0; f < FOUT; f++) {
            hh[f] = (_Float16)acc[f];
            s1 += acc[f] * sa[f];
            s2 += acc[f] * sd[f];
        }
        uint4* hrow = (uint4*)(hT + (long long)n * 16);
        hrow[0] = ((uint4*)hh)[0];
        hrow[1] = ((uint4*)hh)[1];
        asrc[n] = s1;
        float2 am; am.x = s1; am.y = s2;
        *(float2*)&meta[n] = am;   // xy only; zw written by binB
    }
}

// ---------------- scatB: exact-slot scatter; LDS cursors; local 391-scan of bsums ----------------
template <int B2>
__global__ void __launch_bounds__(1024)
k_scatB(const int* __restrict__ esrc, const int* __restrict__ edst, int E,
        const int* __restrict__ sexcl, const int* __restrict__ bsums,
        int* __restrict__ tmp, int NBUK) {
    __shared__ int cur[NBUK_MAX];
    __shared__ int bex[512];
    int t = threadIdx.x, b = blockIdx.x;
    if (t < 512) bex[t] = (t < NBUK) ? bsums[t] : 0;
    __syncthreads();
    for (int off = 1; off < 512; off <<= 1) {            // inclusive scan, 512 wide
        int a = (t < 512 && t >= off) ? bex[t - off] : 0;
        __syncthreads();
        if (t < 512) bex[t] += a;
        __syncthreads();
    }
    for (int k = t; k < NBUK; k += 1024)
        cur[k] = sexcl[(long long)k * B2 + b] + (k ? bex[k - 1] : 0);
    __syncthreads();
    long long ebeg = (long long)b * E / B2, eend = (long long)(b + 1) * E / B2;
    for (long long i = ebeg + t; i < eend; i += 1024) {
        int d = __builtin_nontemporal_load(&edst[i]);
        int sv = __builtin_nontemporal_load(&esrc[i]);
        int pos = atomicAdd(&cur[d >> 8], 1);
        tmp[pos] = ((d & 255) << 17) | sv;   // src < 2^17; cached store (coalesces in L2)
    }
}

// ---------------- binB: 256-dst buckets; degree-sort; bin to sorted csr slots ----------------
// 512 threads: edge loops stride 512; sort/scan sections run on low 256 threads.
// Also writes perm (degree-descending schedule) and {r0,r1} into meta[d].zw.
template <int B2>
__global__ void __launch_bounds__(512)
k_binB(const int* __restrict__ sexcl, const int* __restrict__ bsums,
       const int* __restrict__ tmp, int* __restrict__ perm, int4* __restrict__ meta,
       int* __restrict__ csr_src, int N, int NBUK, int E) {
    __shared__ int bx[512];
    __shared__ int cnt[256];
    __shared__ int h1[256];
    __shared__ int h2[256];
    __shared__ int sdv[256];
    __shared__ int ssc[256];
    __shared__ int cur[256];
    int t = threadIdx.x, b = blockIdx.x;
    bx[t] = (t < NBUK) ? bsums[t] : 0;
    __syncthreads();
    for (int off = 1; off < 512; off <<= 1) {            // inclusive scan, 512 wide
        int a = (t >= off) ? bx[t - off] : 0;
        __syncthreads();
        bx[t] += a;
        __syncthreads();
    }
    int t0 = sexcl[(long long)b * B2] + (b ? bx[b - 1] : 0);
    int t1 = (b + 1 < NBUK) ? (sexcl[(long long)(b + 1) * B2] + bx[b]) : E;
    if (t < 256) cnt[t] = 0;
    __syncthreads();
    for (int i = t0 + t; i < t1; i += 512)
        atomicAdd(&cnt[__builtin_nontemporal_load(&tmp[i]) >> 17], 1);
    __syncthreads();
    int d = b * 256 + t;
    bool valid = (t < 256) && (d < N);
    int dg = (t < 256) ? cnt[t] : 0;      // full degree of dst d

    // counting sort by descending degree (low 256 threads)
    if (t < 256) h1[t] = 0;
    __syncthreads();
    int key = 255 - min(dg, 255);
    if (valid) atomicAdd(&h1[key], 1);
    __syncthreads();
    int v = (t < 256) ? h1[t] : 0;
    if (t < 256) h2[t] = v;
    __syncthreads();
    for (int off = 1; off < 256; off <<= 1) {
        int a = (t < 256 && t >= off) ? h2[t - off] : 0;
        __syncthreads();
        if (t < 256) h2[t] += a;
        __syncthreads();
    }
    if (t < 256) h1[t] = h2[t] - v;      // exclusive base -> bin cursor
    __syncthreads();
    int r = 0;
    if (valid) r = atomicAdd(&h1[key], 1);

    // exclusive scan of degrees in sorted order
    if (t < 256) sdv[t] = 0;
    __syncthreads();
    if (valid) sdv[r] = dg;
    __syncthreads();
    int sv = (t < 256) ? sdv[t] : 0;
    if (t < 256) ssc[t] = sv;
    __syncthreads();
    for (int off = 1; off < 256; off <<= 1) {
        int a = (t < 256 && t >= off) ? ssc[t - off] : 0;
        __syncthreads();
        if (t < 256) ssc[t] += a;
        __syncthreads();
    }
    if (valid) {
        int base = t0 + ssc[r] - dg;  // exclusive offset at rank r (sorted layout)
        cur[t] = base;                // cursor indexed by dst low-bits (scatter key)
        perm[b * 256 + r] = d;        // only last bucket is partial -> perm[0..N) dense
        int2 m; m.x = base; m.y = base + dg;
        *(int2*)((char*)&meta[d] + 8) = m;   // meta.zw = {r0, r1}
    }
    __syncthreads();
    for (int i = t0 + t; i < t1; i += 512) {
        int p = __builtin_nontemporal_load(&tmp[i]);
        int pos = atomicAdd(&cur[p >> 17], 1);
        csr_src[pos] = p & 0x1FFFF;   // cached store (coalesces in L2)
    }
}

// ---------------- GAT aggregation core: 4-lane groups; 2-deep software pipeline ----------------
// Stages per chunk of 4 edges: LOAD (csr+asrc, 2 ahead) / MID (p, shfl, issue H gathers, 1 ahead)
// / FMA (consume H issued last iteration). Keeps ~6-7 loads in flight per wave.
template <typename EPI>
__device__ __forceinline__ void gat_core4(const _Float16* __restrict__ hT,
                                          const float* __restrict__ asrc,
                                          const int4* __restrict__ meta,
                                          const int* __restrict__ csr_src,
                                          int d, int l4, EPI epilogue) {
    const char* __restrict__ Hb = (const char*)hT;     // row s at byte s*32; lane slice +l4*8
    int4 m = meta[d];
    float as_d = __int_as_float(m.x);
    float ad   = __int_as_float(m.y);
    int r0 = m.z, r1 = m.w;

    // self loop
    float e0 = as_d + ad;
    e0 = (e0 >= 0.f) ? e0 : NEG_SLOPE * e0;
    float p0 = __expf(e0);
    h4v hd = *(const h4v*)(Hb + (((unsigned)d) << 5) + (l4 << 3));
    float a0 = p0 * (float)hd[0], a1 = p0 * (float)hd[1];
    float a2 = p0 * (float)hd[2], a3 = p0 * (float)hd[3];
    float psum = (l4 == 0) ? p0 : 0.f;

    int rem = r1 - r0;
    if (rem > 0) {
        int nch = (rem + 3) >> 2;

#define GLOAD(S, AV, c) do { \
        int jj = r0 + ((c) << 2) + l4; \
        int jc = (jj < r1) ? jj : r0; \
        int sr = __builtin_nontemporal_load(&csr_src[jc]); \
        S = (jj < r1) ? sr : d; \
        AV = asrc[S]; } while (0)

#define GMID(S, AV, P0, P1, P2, P3, H0, H1, H2, H3, c) do { \
        int jj = r0 + ((c) << 2) + l4; \
        float e = AV + ad; e = (e >= 0.f) ? e : NEG_SLOPE * e; \
        float p = (jj < r1) ? __expf(e) : 0.f; \
        psum += p; \
        P0 = __shfl(p, 0, 4); { int sk = __shfl(S, 0, 4); H0 = *(const h4v*)(Hb + (((unsigned)sk) << 5) + (l4 << 3)); } \
        P1 = __shfl(p, 1, 4); { int sk = __shfl(S, 1, 4); H1 = *(const h4v*)(Hb + (((unsigned)sk) << 5) + (l4 << 3)); } \
        P2 = __shfl(p, 2, 4); { int sk = __shfl(S, 2, 4); H2 = *(const h4v*)(Hb + (((unsigned)sk) << 5) + (l4 << 3)); } \
        P3 = __shfl(p, 3, 4); { int sk = __shfl(S, 3, 4); H3 = *(const h4v*)(Hb + (((unsigned)sk) << 5) + (l4 << 3)); } } while (0)

#define GFMA(P0, P1, P2, P3, H0, H1, H2, H3) do { \
        a0 += P0 * (float)H0[0]; a1 += P0 * (float)H0[1]; a2 += P0 * (float)H0[2]; a3 += P0 * (float)H0[3]; \
        a0 += P1 * (float)H1[0]; a1 += P1 * (float)H1[1]; a2 += P1 * (float)H1[2]; a3 += P1 * (float)H1[3]; \
        a0 += P2 * (float)H2[0]; a1 += P2 * (float)H2[1]; a2 += P2 * (float)H2[2]; a3 += P2 * (float)H2[3]; \
        a0 += P3 * (float)H3[0]; a1 += P3 * (float)H3[1]; a2 += P3 * (float)H3[2]; a3 += P3 * (float)H3[3]; } while (0)

        int   sA, sB, sC = d;
        float avA, avB, avC = 0.f;
        float pA0, pA1, pA2, pA3, pB0, pB1, pB2, pB3;
        h4v   hA0, hA1, hA2, hA3, hB0, hB1, hB2, hB3;

        GLOAD(sA, avA, 0);
        if (nch > 1) GLOAD(sB, avB, 1);
        GMID(sA, avA, pA0, pA1, pA2, pA3, hA0, hA1, hA2, hA3, 0);
        int c = 0;
        while (c + 1 < nch) {
            if (c + 2 < nch) GLOAD(sC, avC, c + 2);
            GMID(sB, avB, pB0, pB1, pB2, pB3, hB0, hB1, hB2, hB3, c + 1);
            GFMA(pA0, pA1, pA2, pA3, hA0, hA1, hA2, hA3);
            pA0 = pB0; pA1 = pB1; pA2 = pB2; pA3 = pB3;
            hA0 = hB0; hA1 = hB1; hA2 = hB2; hA3 = hB3;
            sB = sC; avB = avC;
            c++;
        }
        GFMA(pA0, pA1, pA2, pA3, hA0, hA1, hA2, hA3);
#undef GLOAD
#undef GMID
#undef GFMA
    }
    psum += __shfl_xor(psum, 1, 4);
    psum += __shfl_xor(psum, 2, 4);
    float inv = 1.f / fmaxf(psum, 1e-16f);
    epilogue(d, r0, r1, a0 * inv, a1 * inv, a2 * inv, a3 * inv);
}

// gat + bias/relu + NEXT-layer transform fused; writes next-layer hT/asrc/meta
template <int FN>
__global__ void __launch_bounds__(256)
k_gat_ft(const _Float16* __restrict__ hT, const float* __restrict__ asrc,
         const int4* __restrict__ meta, const int* __restrict__ csr_src,
         const int* __restrict__ perm, const float* __restrict__ bias,
         const float* __restrict__ Wn, const float* __restrict__ an_src,
         const float* __restrict__ an_dst,
         _Float16* __restrict__ hT_n, float* __restrict__ asrc_n,
         int4* __restrict__ meta_n, int N) {
    __shared__ float sW[16 * 16];
    __shared__ float sa[16], sd[16], sb[16];
    int t = threadIdx.x;
    {
        int k = t >> 4, f = t & 15;
        sW[t] = (f < FN) ? Wn[k * FN + f] : 0.f;
    }
    if (t < 16) {
        sa[t] = (t < FN) ? an_src[t] : 0.f;
        sd[t] = (t < FN) ? an_dst[t] : 0.f;
        sb[t] = bias[t];
    }
    __syncthreads();

    int gid = blockIdx.x * 256 + t;
    int grp = gid >> 2, l4 = gid & 3;
    if (grp >= N) return;
    int d = perm[grp];

    gat_core4(hT, asrc, meta, csr_src, d, l4,
        [&](int dd, int r0, int r1, float v0, float v1, float v2, float v3) {
            int f0 = l4 * 4;
            float vv[4];
            vv[0] = fmaxf(v0 + sb[f0    ], 0.f);
            vv[1] = fmaxf(v1 + sb[f0 + 1], 0.f);
            vv[2] = fmaxf(v2 + sb[f0 + 2], 0.f);
            vv[3] = fmaxf(v3 + sb[f0 + 3], 0.f);
            float o0 = 0.f, o1 = 0.f, o2 = 0.f, o3 = 0.f;
#pragma unroll
            for (int q = 0; q < 4; q++) {
#pragma unroll
                for (int i = 0; i < 4; i++) {
                    float vk = __shfl(vv[i], q, 4);      // broadcast feature k=q*4+i of dst
                    const float* wr = &sW[(q * 4 + i) * 16 + f0];
                    o0 += vk * wr[0];
                    o1 += vk * wr[1];
                    o2 += vk * wr[2];
                    o3 += vk * wr[3];
                }
            }
            float c1 = o0 * sa[f0] + o1 * sa[f0 + 1] + o2 * sa[f0 + 2] + o3 * sa[f0 + 3];
            float c2 = o0 * sd[f0] + o1 * sd[f0 + 1] + o2 * sd[f0 + 2] + o3 * sd[f0 + 3];
            c1 += __shfl_xor(c1, 1, 4); c1 += __shfl_xor(c1, 2, 4);
            c2 += __shfl_xor(c2, 1, 4); c2 += __shfl_xor(c2, 2, 4);
            h4v ho = { (_Float16)o0, (_Float16)o1, (_Float16)o2, (_Float16)o3 };
            ((h4v*)hT_n)[(long long)dd * 4 + l4] = ho;
            if (l4 == 0) {
                asrc_n[dd] = c1;
                int4 mm;
                mm.x = __float_as_int(c1); mm.y = __float_as_int(c2);
                mm.z = r0; mm.w = r1;
                meta_n[dd] = mm;
            }
        });
}

// final gat: fp32 out rows padded to stride 16 (cols >=10 are zero)
__global__ void __launch_bounds__(256)
k_gat_last(const _Float16* __restrict__ hT, const float* __restrict__ asrc,
           const int4* __restrict__ meta, const int* __restrict__ csr_src,
           const int* __restrict__ perm, float* __restrict__ out, int N) {
    int gid = blockIdx.x * 256 + threadIdx.x;
    int grp = gid >> 2, l4 = gid & 3;
    if (grp >= N) return;
    int d = perm[grp];
    gat_core4(hT, asrc, meta, csr_src, d, l4,
        [&](int dd, int r0, int r1, float v0, float v1, float v2, float v3) {
            v4f o = { v0, v1, v2, v3 };
            ((v4f*)out)[(long long)dd * 4 + l4] = o;
        });
}

// ---------------- pool + softmax (h3 rows have stride 16) ----------------
__global__ void k_pool(const float* __restrict__ h3, const int* __restrict__ batch,
                       const float* __restrict__ b3, float* __restrict__ out, int N, int C) {
    int g = blockIdx.x;
    int lo = 0, hi = N;
    while (lo < hi) { int mid = (lo + hi) >> 1; if (batch[mid] < g) lo = mid + 1; else hi = mid; }
    int start = lo;
    hi = N;
    while (lo < hi) { int mid = (lo + hi) >> 1; if (batch[mid] < g + 1) lo = mid + 1; else hi = mid; }
    int end = lo;

    float sum[16];
    for (int f = 0; f < C; f++) sum[f] = 0.f;
    for (int n = start + threadIdx.x; n < end; n += blockDim.x) {
        const float* r = h3 + (long long)n * 16;
        for (int f = 0; f < C; f++) sum[f] += r[f];
    }
    __shared__ float red[256 * 16];
    for (int f = 0; f < C; f++) red[threadIdx.x * 16 + f] = sum[f];
    __syncthreads();
    for (int str = blockDim.x / 2; str > 0; str >>= 1) {
        if ((int)threadIdx.x < str)
            for (int f = 0; f < C; f++) red[threadIdx.x * 16 + f] += red[(threadIdx.x + str) * 16 + f];
        __syncthreads();
    }
    if (threadIdx.x == 0) {
        float cnt = fmaxf((float)(end - start), 1.f);
        float vals[16];
        float mx = -INFINITY;
        for (int f = 0; f < C; f++) { vals[f] = red[f] / cnt + b3[f]; mx = fmaxf(mx, vals[f]); }
        float se = 0.f;
        for (int f = 0; f < C; f++) { vals[f] = __expf(vals[f] - mx); se += vals[f]; }
        for (int f = 0; f < C; f++) out[(long long)g * C + f] = vals[f] / se;
    }
}

extern "C" void kernel_launch(void* const* d_in, const int* in_sizes, int n_in,
                              void* d_out, int out_size, void* d_ws, size_t ws_size,
                              hipStream_t stream) {
    const float* x    = (const float*)d_in[0];
    const int*   eidx = (const int*)d_in[1];
    const int*   batch= (const int*)d_in[2];
    const float* emb  = (const float*)d_in[3];
    const float* W1   = (const float*)d_in[4];
    const float* as1  = (const float*)d_in[5];
    const float* ad1  = (const float*)d_in[6];
    const float* b1   = (const float*)d_in[7];
    const float* W2   = (const float*)d_in[8];
    const float* as2  = (const float*)d_in[9];
    const float* ad2  = (const float*)d_in[10];
    const float* b2   = (const float*)d_in[11];
    const float* W3   = (const float*)d_in[12];
    const float* as3  = (const float*)d_in[13];
    const float* ad3  = (const float*)d_in[14];
    const float* b3   = (const float*)d_in[15];

    const int H = in_sizes[5];          // 16
    const int C = in_sizes[13];         // 10
    const int D = in_sizes[4] / H;      // 50
    const int V = in_sizes[3] / D;      // 128
    const int N = in_sizes[0] / V;      // 100000
    const int E = in_sizes[1] / 2;      // 1600000
    const int G = out_size / C;         // 512
    const int* esrc = eidx;
    const int* edst = eidx + E;
    const int NBUK = (N + 255) >> 8;    // 391 buckets of 256 dsts (must be <=512)
    constexpr int B2 = 256;             // scatter blocks; bucket runs ~16 entries = one 64B line
    const int M = NBUK * B2;            // histT elements (100K)

    char* w = (char*)d_ws;
    auto carve = [&](size_t bytes) {
        char* p = w;
        w += (bytes + 255) & ~(size_t)255;
        return p;
    };
    int*      idx     = (int*)carve((size_t)N * 4);
    int*      perm    = (int*)carve((size_t)N * 4);
    int*      histT   = (int*)carve((size_t)M * 4);
    int*      sexcl   = (int*)carve((size_t)M * 4);
    int*      bsums   = (int*)carve(2048 * 4);
    int*      csr_src = (int*)carve((size_t)E * 4);
    _Float16* hTa     = (_Float16*)carve((size_t)N * 32);
    _Float16* hTb     = (_Float16*)carve((size_t)N * 32);
    float*    asA     = (float*)carve((size_t)N * 4);
    float*    asB     = (float*)carve((size_t)N * 4);
    int4*     metaA   = (int4*)carve((size_t)N * 16);
    int4*     metaB   = (int4*)carve((size_t)N * 16);
    size_t zone_bytes = ((size_t)E * 4 > (size_t)N * 64) ? (size_t)E * 4 : (size_t)N * 64;
    char*  zone = carve(zone_bytes);
    float* X0  = (float*)zone;          // N x 16 fp32 padded rows (after tmp is dead)
    int*   tmp = (int*)zone;
    (void)ws_size; (void)n_in;

    const int BT = 256;
    dim3 blk(BT);
    int gGat4 = (N * 4 + BT - 1) / BT;      // 4 lanes per dst
    int nb2   = (M + 255) / 256;            // scan blocks over histT (= NBUK = 391)
    int gArg  = (N + 31) / 32;              // argmax blocks (32 nodes per 1024-thr block)
    int gTr   = (N + BT - 1) / BT;          // transform blocks

    // ---- K_A: histB (LDS bucket hist) + argmax in one launch ----
    k_histarg<B2><<<B2 + gArg, dim3(1024), 0, stream>>>(x, edst, E, histT, NBUK, idx, N, V);

    // ---- K_B: scan1 + layer-1 transform in one launch (bsums stay raw chunk sums) ----
    k_scan_tr<50, 16><<<nb2 + gTr, blk, 0, stream>>>(histT, sexcl, bsums, M,
                                                     emb, idx, W1, as1, ad1,
                                                     hTa, asA, metaA, N, nb2);

    // ---- scatter to bucket-ordered tmp, then bin to degree-sorted CSR slots ----
    k_scatB<B2><<<B2, dim3(1024), 0, stream>>>(esrc, edst, E, sexcl, bsums, tmp, NBUK);
    k_binB<B2><<<NBUK, dim3(512), 0, stream>>>(sexcl, bsums, tmp, perm, metaA, csr_src, N, NBUK, E);

    // ---- gat1 (+b1,relu) fused with transform2 -> hTb/asB/metaB ----
    k_gat_ft<16><<<gGat4, blk, 0, stream>>>(hTa, asA, metaA, csr_src, perm, b1,
                                            W2, as2, ad2, hTb, asB, metaB, N);

    // ---- gat2 (+b2,relu) fused with transform3 -> hTa/asA/metaA ----
    k_gat_ft<10><<<gGat4, blk, 0, stream>>>(hTb, asB, metaB, csr_src, perm, b2,
                                            W3, as3, ad3, hTa, asA, metaA, N);

    // ---- gat3 -> X0 (N x 16 fp32, cols >=10 zero) ----
    k_gat_last<<<gGat4, blk, 0, stream>>>(hTa, asA, metaA, csr_src, perm, X0, N);

    // ---- pool + softmax ----
    k_pool<<<G, blk, 0, stream>>>(X0, batch, b3, (float*)d_out, N, C);
}

// Round 7
// 278.788 us; speedup vs baseline: 1.1174x; 1.1174x over previous
//
#include <hip/hip_runtime.h>
#include <math.h>

#define NEG_SLOPE 0.2f
#define NBUK_MAX 512    // LDS capacity for bucket counters (buckets of 256 dsts; NBUK=391, must be <=512)

typedef float v4f __attribute__((ext_vector_type(4)));
typedef _Float16 h4v __attribute__((ext_vector_type(4)));   // 8B: 4 packed fp16 features

// Per-node hot data (per-edge random gather, must stay L2-resident, 3.2MB):
//   hT: N x 16 f16 (32B rows) - the ONLY per-edge gather. alpha_src[s] is RECOMPUTED
//   in-register from the gathered row (dot with a_src + 4-lane shfl reduce): round 6
//   showed the GAT kernels are bound by per-CU memory-request throughput (~2.25
//   line-requests/edge), not VALU (8.7%) nor ILP (manual pipelining was null) — dropping
//   the separate asrc gather cuts requests to ~1.25/edge.
// Per-dst data (read once): meta int4 {asrc_exact(f32), adst(f32), r0, r1}.
// Streams (edst/esrc/tmp/csr_src/x) use NT *loads* only; scattered stores stay cached
// (NT scattered stores = ~16x write amplification, measured round 4).

// ---------------- K_A: histB (blocks 0..B2) UNION argmax (rest) ----------------
template <int B2>
__global__ void __launch_bounds__(1024)
k_histarg(const float* __restrict__ x, const int* __restrict__ edst, int E,
          int* __restrict__ histT, int NBUK, int* __restrict__ idx, int N, int V) {
    __shared__ int sh[NBUK_MAX];
    int t = threadIdx.x;
    if ((int)blockIdx.x < B2) {
        int b = blockIdx.x;
        for (int k = t; k < NBUK; k += 1024) sh[k] = 0;
        __syncthreads();
        long long ebeg = (long long)b * E / B2, eend = (long long)(b + 1) * E / B2;
        for (long long i = ebeg + t; i < eend; i += 1024)
            atomicAdd(&sh[__builtin_nontemporal_load(&edst[i]) >> 8], 1);
        __syncthreads();
        for (int k = t; k < NBUK; k += 1024) histT[(long long)k * B2 + b] = sh[k];
    } else {
        int node = ((int)blockIdx.x - B2) * 32 + (t >> 5);
        int lane = t & 31;
        if (node >= N) return;
        const v4f* row = (const v4f*)(x + (long long)node * V);
        float bv = -INFINITY;
        int bi = 0x7fffffff;
        int nq = V >> 2;
        for (int q = lane; q < nq; q += 32) {
            v4f v = __builtin_nontemporal_load(&row[q]);
            int base = q << 2;
            if (v.x > bv || (v.x == bv && base     < bi)) { bv = v.x; bi = base;     }
            if (v.y > bv || (v.y == bv && base + 1 < bi)) { bv = v.y; bi = base + 1; }
            if (v.z > bv || (v.z == bv && base + 2 < bi)) { bv = v.z; bi = base + 2; }
            if (v.w > bv || (v.w == bv && base + 3 < bi)) { bv = v.w; bi = base + 3; }
        }
        for (int off = 16; off > 0; off >>= 1) {
            float ov = __shfl_down(bv, off, 32);
            int   oi = __shfl_down(bi, off, 32);
            if (ov > bv || (ov == bv && oi < bi)) { bv = ov; bi = oi; }
        }
        if (lane == 0) idx[node] = bi;
    }
}

// ---------------- K_B: scan1 (blocks 0..NB_SCAN) UNION layer-1 transform (rest) ----------------
// Transform writes hT rows and meta.xy = {asrc,adst}. r0/r1 (meta.zw) filled by binB.
template <int FIN, int FOUT>
__global__ void __launch_bounds__(256)
k_scan_tr(const int* __restrict__ vals, int* __restrict__ excl, int* __restrict__ bsums, int M,
          const float* __restrict__ emb, const int* __restrict__ idx,
          const float* __restrict__ W, const float* __restrict__ a_src,
          const float* __restrict__ a_dst, _Float16* __restrict__ hT,
          int4* __restrict__ meta, int N, int NB_SCAN) {
    __shared__ int s[256];
    __shared__ float sW[FIN * FOUT];
    __shared__ float sa[FOUT], sd[FOUT];
    int t = threadIdx.x;
    if ((int)blockIdx.x < NB_SCAN) {
        int i = blockIdx.x * 256 + t;
        int v = (i < M) ? vals[i] : 0;
        s[t] = v;
        __syncthreads();
        for (int off = 1; off < 256; off <<= 1) {
            int a = (t >= off) ? s[t - off] : 0;
            __syncthreads();
            s[t] += a;
            __syncthreads();
        }
        if (i < M) excl[i] = s[t] - v;
        if (t == 255) bsums[blockIdx.x] = s[255];   // raw chunk sums (scanned locally by consumers)
    } else {
        for (int i = t; i < FIN * FOUT; i += 256) sW[i] = W[i];
        if (t < FOUT) { sa[t] = a_src[t]; sd[t] = a_dst[t]; }
        __syncthreads();
        int n = ((int)blockIdx.x - NB_SCAN) * 256 + t;
        if (n >= N) return;
        float acc[FOUT];
#pragma unroll
        for (int f = 0; f < FOUT; f++) acc[f] = 0.f;
        const float* hr = emb + (long long)idx[n] * FIN;
        for (int k = 0; k < FIN; k++) {
            float v = hr[k];
#pragma unroll
            for (int f = 0; f < FOUT; f++) acc[f] += v * sW[k * FOUT + f];
        }
        float s1 = 0.f, s2 = 0.f;
        _Float16 hh[16];
#pragma unroll
        for (int f = 0; f < 16; f++) hh[f] = (_Float16)0.f;
#pragma unroll
        for (int f = 0; f < FOUT; f++) {
            hh[f] = (_Float16)acc[f];
            s1 += acc[f] * sa[f];
            s2 += acc[f] * sd[f];
        }
        uint4* hrow = (uint4*)(hT + (long long)n * 16);
        hrow[0] = ((uint4*)hh)[0];
        hrow[1] = ((uint4*)hh)[1];
        float2 am; am.x = s1; am.y = s2;
        *(float2*)&meta[n] = am;   // xy only; zw written by binB
    }
}

// ---------------- scatB: exact-slot scatter; LDS cursors; local 391-scan of bsums ----------------
template <int B2>
__global__ void __launch_bounds__(1024)
k_scatB(const int* __restrict__ esrc, const int* __restrict__ edst, int E,
        const int* __restrict__ sexcl, const int* __restrict__ bsums,
        int* __restrict__ tmp, int NBUK) {
    __shared__ int cur[NBUK_MAX];
    __shared__ int bex[512];
    int t = threadIdx.x, b = blockIdx.x;
    if (t < 512) bex[t] = (t < NBUK) ? bsums[t] : 0;
    __syncthreads();
    for (int off = 1; off < 512; off <<= 1) {            // inclusive scan, 512 wide
        int a = (t < 512 && t >= off) ? bex[t - off] : 0;
        __syncthreads();
        if (t < 512) bex[t] += a;
        __syncthreads();
    }
    for (int k = t; k < NBUK; k += 1024)
        cur[k] = sexcl[(long long)k * B2 + b] + (k ? bex[k - 1] : 0);
    __syncthreads();
    long long ebeg = (long long)b * E / B2, eend = (long long)(b + 1) * E / B2;
    for (long long i = ebeg + t; i < eend; i += 1024) {
        int d = __builtin_nontemporal_load(&edst[i]);
        int sv = __builtin_nontemporal_load(&esrc[i]);
        int pos = atomicAdd(&cur[d >> 8], 1);
        tmp[pos] = ((d & 255) << 17) | sv;   // src < 2^17; cached store (coalesces in L2)
    }
}

// ---------------- binB: 256-dst buckets; degree-sort; bin to sorted csr slots ----------------
// 512 threads: edge loops stride 512; sort/scan sections run on low 256 threads.
// Also writes perm (degree-descending schedule) and {r0,r1} into meta[d].zw.
template <int B2>
__global__ void __launch_bounds__(512)
k_binB(const int* __restrict__ sexcl, const int* __restrict__ bsums,
       const int* __restrict__ tmp, int* __restrict__ perm, int4* __restrict__ meta,
       int* __restrict__ csr_src, int N, int NBUK, int E) {
    __shared__ int bx[512];
    __shared__ int cnt[256];
    __shared__ int h1[256];
    __shared__ int h2[256];
    __shared__ int sdv[256];
    __shared__ int ssc[256];
    __shared__ int cur[256];
    int t = threadIdx.x, b = blockIdx.x;
    bx[t] = (t < NBUK) ? bsums[t] : 0;
    __syncthreads();
    for (int off = 1; off < 512; off <<= 1) {            // inclusive scan, 512 wide
        int a = (t >= off) ? bx[t - off] : 0;
        __syncthreads();
        bx[t] += a;
        __syncthreads();
    }
    int t0 = sexcl[(long long)b * B2] + (b ? bx[b - 1] : 0);
    int t1 = (b + 1 < NBUK) ? (sexcl[(long long)(b + 1) * B2] + bx[b]) : E;
    if (t < 256) cnt[t] = 0;
    __syncthreads();
    for (int i = t0 + t; i < t1; i += 512)
        atomicAdd(&cnt[__builtin_nontemporal_load(&tmp[i]) >> 17], 1);
    __syncthreads();
    int d = b * 256 + t;
    bool valid = (t < 256) && (d < N);
    int dg = (t < 256) ? cnt[t] : 0;      // full degree of dst d

    // counting sort by descending degree (low 256 threads)
    if (t < 256) h1[t] = 0;
    __syncthreads();
    int key = 255 - min(dg, 255);
    if (valid) atomicAdd(&h1[key], 1);
    __syncthreads();
    int v = (t < 256) ? h1[t] : 0;
    if (t < 256) h2[t] = v;
    __syncthreads();
    for (int off = 1; off < 256; off <<= 1) {
        int a = (t < 256 && t >= off) ? h2[t - off] : 0;
        __syncthreads();
        if (t < 256) h2[t] += a;
        __syncthreads();
    }
    if (t < 256) h1[t] = h2[t] - v;      // exclusive base -> bin cursor
    __syncthreads();
    int r = 0;
    if (valid) r = atomicAdd(&h1[key], 1);

    // exclusive scan of degrees in sorted order
    if (t < 256) sdv[t] = 0;
    __syncthreads();
    if (valid) sdv[r] = dg;
    __syncthreads();
    int sv = (t < 256) ? sdv[t] : 0;
    if (t < 256) ssc[t] = sv;
    __syncthreads();
    for (int off = 1; off < 256; off <<= 1) {
        int a = (t < 256 && t >= off) ? ssc[t - off] : 0;
        __syncthreads();
        if (t < 256) ssc[t] += a;
        __syncthreads();
    }
    if (valid) {
        int base = t0 + ssc[r] - dg;  // exclusive offset at rank r (sorted layout)
        cur[t] = base;                // cursor indexed by dst low-bits (scatter key)
        perm[b * 256 + r] = d;        // only last bucket is partial -> perm[0..N) dense
        int2 m; m.x = base; m.y = base + dg;
        *(int2*)((char*)&meta[d] + 8) = m;   // meta.zw = {r0, r1}
    }
    __syncthreads();
    for (int i = t0 + t; i < t1; i += 512) {
        int p = __builtin_nontemporal_load(&tmp[i]);
        int pos = atomicAdd(&cur[p >> 17], 1);
        csr_src[pos] = p & 0x1FFFF;   // cached store (coalesces in L2)
    }
}

// ---------------- GAT aggregation core: 4-lane groups; single H gather per edge ----------------
// alpha_src[s] recomputed in-register: dot(h_slice, aw) + 2x shfl_xor(,,4). p is
// group-uniform -> psum needs no final reduce and no p-broadcast shfls.
template <typename EPI>
__device__ __forceinline__ void gat_core4(const _Float16* __restrict__ hT,
                                          v4f aw,                       // lane's 4 a_src weights
                                          const int4* __restrict__ meta,
                                          const int* __restrict__ csr_src,
                                          int d, int l4, EPI epilogue) {
    const char* __restrict__ Hb = (const char*)hT;     // row s at byte s*32; lane slice +l4*8
    int4 m = meta[d];
    float as_d = __int_as_float(m.x);
    float ad   = __int_as_float(m.y);
    int r0 = m.z, r1 = m.w;

    // self loop (exact f32 asrc from meta)
    float e0 = as_d + ad;
    e0 = (e0 >= 0.f) ? e0 : NEG_SLOPE * e0;
    float p0 = __expf(e0);
    h4v hd = *(const h4v*)(Hb + (((unsigned)d) << 5) + (l4 << 3));
    float a0 = p0 * (float)hd[0], a1 = p0 * (float)hd[1];
    float a2 = p0 * (float)hd[2], a3 = p0 * (float)hd[3];
    float psum = p0;                                   // group-uniform accumulation

    int rem = r1 - r0;
    if (rem > 0) {
        int nch = (rem + 3) >> 2;

#define SLOAD(S, c) do { \
        int jj = r0 + ((c) << 2) + l4; \
        int jc = (jj < r1) ? jj : r0; \
        int sr = __builtin_nontemporal_load(&csr_src[jc]); \
        S = (jj < r1) ? sr : d; } while (0)

#define HGATH(S, H0, H1, H2, H3) do { \
        { int sk = __shfl(S, 0, 4); H0 = *(const h4v*)(Hb + (((unsigned)sk) << 5) + (l4 << 3)); } \
        { int sk = __shfl(S, 1, 4); H1 = *(const h4v*)(Hb + (((unsigned)sk) << 5) + (l4 << 3)); } \
        { int sk = __shfl(S, 2, 4); H2 = *(const h4v*)(Hb + (((unsigned)sk) << 5) + (l4 << 3)); } \
        { int sk = __shfl(S, 3, 4); H3 = *(const h4v*)(Hb + (((unsigned)sk) << 5) + (l4 << 3)); } } while (0)

#define PEDGE(Hk, kk, c) do { \
        float f0 = (float)Hk[0], f1 = (float)Hk[1], f2 = (float)Hk[2], f3 = (float)Hk[3]; \
        float dt = f0 * aw.x + f1 * aw.y + f2 * aw.z + f3 * aw.w; \
        dt += __shfl_xor(dt, 1, 4); \
        dt += __shfl_xor(dt, 2, 4); \
        float e = dt + ad; \
        e = (e >= 0.f) ? e : NEG_SLOPE * e; \
        float p = (r0 + ((c) << 2) + (kk) < r1) ? __expf(e) : 0.f; \
        psum += p; \
        a0 += p * f0; a1 += p * f1; a2 += p * f2; a3 += p * f3; } while (0)

#define PROC(H0, H1, H2, H3, c) do { \
        PEDGE(H0, 0, c); PEDGE(H1, 1, c); PEDGE(H2, 2, c); PEDGE(H3, 3, c); } while (0)

        int sA, sB = d, sC = d;
        h4v hA0, hA1, hA2, hA3, hB0, hB1, hB2, hB3;

        SLOAD(sA, 0);
        HGATH(sA, hA0, hA1, hA2, hA3);
        if (nch > 1) SLOAD(sB, 1);
        int c = 0;
        while (c + 1 < nch) {
            if (c + 2 < nch) SLOAD(sC, c + 2);
            HGATH(sB, hB0, hB1, hB2, hB3);     // issue next chunk's gathers
            PROC(hA0, hA1, hA2, hA3, c);       // consume current chunk
            hA0 = hB0; hA1 = hB1; hA2 = hB2; hA3 = hB3;
            sB = sC;
            c++;
        }
        PROC(hA0, hA1, hA2, hA3, c);
#undef SLOAD
#undef HGATH
#undef PEDGE
#undef PROC
    }
    float inv = 1.f / fmaxf(psum, 1e-16f);
    epilogue(d, r0, r1, a0 * inv, a1 * inv, a2 * inv, a3 * inv);
}

// gat + bias/relu + NEXT-layer transform fused; writes next-layer hT/meta
template <int FN>
__global__ void __launch_bounds__(256)
k_gat_ft(const _Float16* __restrict__ hT, const int4* __restrict__ meta,
         const int* __restrict__ csr_src, const int* __restrict__ perm,
         const float* __restrict__ a_cur,       // current-layer a_src (16 entries)
         const float* __restrict__ bias,
         const float* __restrict__ Wn, const float* __restrict__ an_src,
         const float* __restrict__ an_dst,
         _Float16* __restrict__ hT_n, int4* __restrict__ meta_n, int N) {
    __shared__ float sW[16 * 16];
    __shared__ float sa[16], sd[16], sb[16];
    int t = threadIdx.x;
    {
        int k = t >> 4, f = t & 15;
        sW[t] = (f < FN) ? Wn[k * FN + f] : 0.f;
    }
    if (t < 16) {
        sa[t] = (t < FN) ? an_src[t] : 0.f;
        sd[t] = (t < FN) ? an_dst[t] : 0.f;
        sb[t] = bias[t];
    }
    __syncthreads();

    int gid = blockIdx.x * 256 + t;
    int grp = gid >> 2, l4 = gid & 3;
    if (grp >= N) return;
    int d = perm[grp];
    int fb = l4 << 2;
    v4f aw = { a_cur[fb], a_cur[fb + 1], a_cur[fb + 2], a_cur[fb + 3] };

    gat_core4(hT, aw, meta, csr_src, d, l4,
        [&](int dd, int r0, int r1, float v0, float v1, float v2, float v3) {
            int f0 = l4 * 4;
            float vv[4];
            vv[0] = fmaxf(v0 + sb[f0    ], 0.f);
            vv[1] = fmaxf(v1 + sb[f0 + 1], 0.f);
            vv[2] = fmaxf(v2 + sb[f0 + 2], 0.f);
            vv[3] = fmaxf(v3 + sb[f0 + 3], 0.f);
            float o0 = 0.f, o1 = 0.f, o2 = 0.f, o3 = 0.f;
#pragma unroll
            for (int q = 0; q < 4; q++) {
#pragma unroll
                for (int i = 0; i < 4; i++) {
                    float vk = __shfl(vv[i], q, 4);      // broadcast feature k=q*4+i of dst
                    const float* wr = &sW[(q * 4 + i) * 16 + f0];
                    o0 += vk * wr[0];
                    o1 += vk * wr[1];
                    o2 += vk * wr[2];
                    o3 += vk * wr[3];
                }
            }
            float c1 = o0 * sa[f0] + o1 * sa[f0 + 1] + o2 * sa[f0 + 2] + o3 * sa[f0 + 3];
            float c2 = o0 * sd[f0] + o1 * sd[f0 + 1] + o2 * sd[f0 + 2] + o3 * sd[f0 + 3];
            c1 += __shfl_xor(c1, 1, 4); c1 += __shfl_xor(c1, 2, 4);
            c2 += __shfl_xor(c2, 1, 4); c2 += __shfl_xor(c2, 2, 4);
            h4v ho = { (_Float16)o0, (_Float16)o1, (_Float16)o2, (_Float16)o3 };
            ((h4v*)hT_n)[(long long)dd * 4 + l4] = ho;
            if (l4 == 0) {
                int4 mm;
                mm.x = __float_as_int(c1); mm.y = __float_as_int(c2);
                mm.z = r0; mm.w = r1;
                meta_n[dd] = mm;
            }
        });
}

// final gat: fp32 out rows padded to stride 16 (cols >=10 are zero); FC = current a_src len
template <int FC>
__global__ void __launch_bounds__(256)
k_gat_last(const _Float16* __restrict__ hT, const int4* __restrict__ meta,
           const int* __restrict__ csr_src, const int* __restrict__ perm,
           const float* __restrict__ a_cur, float* __restrict__ out, int N) {
    int gid = blockIdx.x * 256 + threadIdx.x;
    int grp = gid >> 2, l4 = gid & 3;
    if (grp >= N) return;
    int d = perm[grp];
    int fb = l4 << 2;
    v4f aw;
    aw.x = (fb     < FC) ? a_cur[fb]     : 0.f;
    aw.y = (fb + 1 < FC) ? a_cur[fb + 1] : 0.f;
    aw.z = (fb + 2 < FC) ? a_cur[fb + 2] : 0.f;
    aw.w = (fb + 3 < FC) ? a_cur[fb + 3] : 0.f;
    gat_core4(hT, aw, meta, csr_src, d, l4,
        [&](int dd, int r0, int r1, float v0, float v1, float v2, float v3) {
            v4f o = { v0, v1, v2, v3 };
            ((v4f*)out)[(long long)dd * 4 + l4] = o;
        });
}

// ---------------- pool + softmax (h3 rows have stride 16) ----------------
__global__ void k_pool(const float* __restrict__ h3, const int* __restrict__ batch,
                       const float* __restrict__ b3, float* __restrict__ out, int N, int C) {
    int g = blockIdx.x;
    int lo = 0, hi = N;
    while (lo < hi) { int mid = (lo + hi) >> 1; if (batch[mid] < g) lo = mid + 1; else hi = mid; }
    int start = lo;
    hi = N;
    while (lo < hi) { int mid = (lo + hi) >> 1; if (batch[mid] < g + 1) lo = mid + 1; else hi = mid; }
    int end = lo;

    float sum[16];
    for (int f = 0; f < C; f++) sum[f] = 0.f;
    for (int n = start + threadIdx.x; n < end; n += blockDim.x) {
        const float* r = h3 + (long long)n * 16;
        for (int f = 0; f < C; f++) sum[f] += r[f];
    }
    __shared__ float red[256 * 16];
    for (int f = 0; f < C; f++) red[threadIdx.x * 16 + f] = sum[f];
    __syncthreads();
    for (int str = blockDim.x / 2; str > 0; str >>= 1) {
        if ((int)threadIdx.x < str)
            for (int f = 0; f < C; f++) red[threadIdx.x * 16 + f] += red[(threadIdx.x + str) * 16 + f];
        __syncthreads();
    }
    if (threadIdx.x == 0) {
        float cnt = fmaxf((float)(end - start), 1.f);
        float vals[16];
        float mx = -INFINITY;
        for (int f = 0; f < C; f++) { vals[f] = red[f] / cnt + b3[f]; mx = fmaxf(mx, vals[f]); }
        float se = 0.f;
        for (int f = 0; f < C; f++) { vals[f] = __expf(vals[f] - mx); se += vals[f]; }
        for (int f = 0; f < C; f++) out[(long long)g * C + f] = vals[f] / se;
    }
}

extern "C" void kernel_launch(void* const* d_in, const int* in_sizes, int n_in,
                              void* d_out, int out_size, void* d_ws, size_t ws_size,
                              hipStream_t stream) {
    const float* x    = (const float*)d_in[0];
    const int*   eidx = (const int*)d_in[1];
    const int*   batch= (const int*)d_in[2];
    const float* emb  = (const float*)d_in[3];
    const float* W1   = (const float*)d_in[4];
    const float* as1  = (const float*)d_in[5];
    const float* ad1  = (const float*)d_in[6];
    const float* b1   = (const float*)d_in[7];
    const float* W2   = (const float*)d_in[8];
    const float* as2  = (const float*)d_in[9];
    const float* ad2  = (const float*)d_in[10];
    const float* b2   = (const float*)d_in[11];
    const float* W3   = (const float*)d_in[12];
    const float* as3  = (const float*)d_in[13];
    const float* ad3  = (const float*)d_in[14];
    const float* b3   = (const float*)d_in[15];

    const int H = in_sizes[5];          // 16
    const int C = in_sizes[13];         // 10
    const int D = in_sizes[4] / H;      // 50
    const int V = in_sizes[3] / D;      // 128
    const int N = in_sizes[0] / V;      // 100000
    const int E = in_sizes[1] / 2;      // 1600000
    const int G = out_size / C;         // 512
    const int* esrc = eidx;
    const int* edst = eidx + E;
    const int NBUK = (N + 255) >> 8;    // 391 buckets of 256 dsts (must be <=512)
    constexpr int B2 = 256;             // scatter blocks; bucket runs ~16 entries = one 64B line
    const int M = NBUK * B2;            // histT elements (100K)

    char* w = (char*)d_ws;
    auto carve = [&](size_t bytes) {
        char* p = w;
        w += (bytes + 255) & ~(size_t)255;
        return p;
    };
    int*      idx     = (int*)carve((size_t)N * 4);
    int*      perm    = (int*)carve((size_t)N * 4);
    int*      histT   = (int*)carve((size_t)M * 4);
    int*      sexcl   = (int*)carve((size_t)M * 4);
    int*      bsums   = (int*)carve(2048 * 4);
    int*      csr_src = (int*)carve((size_t)E * 4);
    _Float16* hTa     = (_Float16*)carve((size_t)N * 32);
    _Float16* hTb     = (_Float16*)carve((size_t)N * 32);
    int4*     metaA   = (int4*)carve((size_t)N * 16);
    int4*     metaB   = (int4*)carve((size_t)N * 16);
    size_t zone_bytes = ((size_t)E * 4 > (size_t)N * 64) ? (size_t)E * 4 : (size_t)N * 64;
    char*  zone = carve(zone_bytes);
    float* X0  = (float*)zone;          // N x 16 fp32 padded rows (after tmp is dead)
    int*   tmp = (int*)zone;
    (void)ws_size; (void)n_in;

    const int BT = 256;
    dim3 blk(BT);
    int gGat4 = (N * 4 + BT - 1) / BT;      // 4 lanes per dst
    int nb2   = (M + 255) / 256;            // scan blocks over histT (= NBUK = 391)
    int gArg  = (N + 31) / 32;              // argmax blocks (32 nodes per 1024-thr block)
    int gTr   = (N + BT - 1) / BT;          // transform blocks

    // ---- K_A: histB (LDS bucket hist) + argmax in one launch ----
    k_histarg<B2><<<B2 + gArg, dim3(1024), 0, stream>>>(x, edst, E, histT, NBUK, idx, N, V);

    // ---- K_B: scan1 + layer-1 transform in one launch (bsums stay raw chunk sums) ----
    k_scan_tr<50, 16><<<nb2 + gTr, blk, 0, stream>>>(histT, sexcl, bsums, M,
                                                     emb, idx, W1, as1, ad1,
                                                     hTa, metaA, N, nb2);

    // ---- scatter to bucket-ordered tmp, then bin to degree-sorted CSR slots ----
    k_scatB<B2><<<B2, dim3(1024), 0, stream>>>(esrc, edst, E, sexcl, bsums, tmp, NBUK);
    k_binB<B2><<<NBUK, dim3(512), 0, stream>>>(sexcl, bsums, tmp, perm, metaA, csr_src, N, NBUK, E);

    // ---- gat1 (+b1,relu) fused with transform2 -> hTb/metaB ----
    k_gat_ft<16><<<gGat4, blk, 0, stream>>>(hTa, metaA, csr_src, perm, as1, b1,
                                            W2, as2, ad2, hTb, metaB, N);

    // ---- gat2 (+b2,relu) fused with transform3 -> hTa/metaA ----
    k_gat_ft<10><<<gGat4, blk, 0, stream>>>(hTb, metaB, csr_src, perm, as2, b2,
                                            W3, as3, ad3, hTa, metaA, N);

    // ---- gat3 -> X0 (N x 16 fp32, cols >=10 zero) ----
    k_gat_last<10><<<gGat4, blk, 0, stream>>>(hTa, metaA, csr_src, perm, as3, X0, N);

    // ---- pool + softmax ----
    k_pool<<<G, blk, 0, stream>>>(X0, batch, b3, (float*)d_out, N, C);
}

// Round 8
// 258.935 us; speedup vs baseline: 1.2030x; 1.0767x over previous
//
#include <hip/hip_runtime.h>
#include <math.h>

#define NEG_SLOPE 0.2f
#define NBUK_MAX 512    // LDS capacity for bucket counters (buckets of 256 dsts; NBUK=391, must be <=512)

typedef float v4f __attribute__((ext_vector_type(4)));
typedef _Float16 h4v __attribute__((ext_vector_type(4)));   // 8B: 4 packed fp16 features

// Per-node hot data (per-edge random gather, must stay L2-resident, 3.2MB):
//   hT: N x 16 f16 (32B rows) - the ONLY per-edge gather. alpha_src[s] is RECOMPUTED
//   in-register from the gathered row (round 6/7: kernels are bound by per-CU memory
//   line-request throughput, not VALU (8.7%) nor ILP; dropping the asrc gather cut
//   requests 2.25 -> 1.25/edge, -33us measured).
// Per-dst data (read once): meta int4 {asrc_exact(f32), adst(f32), r0, r1}.
// NO degree-sort/perm (round 8): d = grp keeps meta/self-row/output accesses SEQUENTIAL
// per wave (the sorted perm randomized them = extra line-requests on the bound resource);
// the divergence it fixed only costs exec-masked VALU issue, which idles at 8.7%.
// Streams (edst/esrc/tmp/csr_src/x) use NT *loads* only; scattered stores stay cached
// (NT scattered stores = ~16x write amplification, measured round 4).

// ---------------- K_A: histB (blocks 0..B2) UNION argmax (rest) ----------------
template <int B2>
__global__ void __launch_bounds__(1024)
k_histarg(const float* __restrict__ x, const int* __restrict__ edst, int E,
          int* __restrict__ histT, int NBUK, int* __restrict__ idx, int N, int V) {
    __shared__ int sh[NBUK_MAX];
    int t = threadIdx.x;
    if ((int)blockIdx.x < B2) {
        int b = blockIdx.x;
        for (int k = t; k < NBUK; k += 1024) sh[k] = 0;
        __syncthreads();
        long long ebeg = (long long)b * E / B2, eend = (long long)(b + 1) * E / B2;
        for (long long i = ebeg + t; i < eend; i += 1024)
            atomicAdd(&sh[__builtin_nontemporal_load(&edst[i]) >> 8], 1);
        __syncthreads();
        for (int k = t; k < NBUK; k += 1024) histT[(long long)k * B2 + b] = sh[k];
    } else {
        int node = ((int)blockIdx.x - B2) * 32 + (t >> 5);
        int lane = t & 31;
        if (node >= N) return;
        const v4f* row = (const v4f*)(x + (long long)node * V);
        float bv = -INFINITY;
        int bi = 0x7fffffff;
        int nq = V >> 2;
        for (int q = lane; q < nq; q += 32) {
            v4f v = __builtin_nontemporal_load(&row[q]);
            int base = q << 2;
            if (v.x > bv || (v.x == bv && base     < bi)) { bv = v.x; bi = base;     }
            if (v.y > bv || (v.y == bv && base + 1 < bi)) { bv = v.y; bi = base + 1; }
            if (v.z > bv || (v.z == bv && base + 2 < bi)) { bv = v.z; bi = base + 2; }
            if (v.w > bv || (v.w == bv && base + 3 < bi)) { bv = v.w; bi = base + 3; }
        }
        for (int off = 16; off > 0; off >>= 1) {
            float ov = __shfl_down(bv, off, 32);
            int   oi = __shfl_down(bi, off, 32);
            if (ov > bv || (ov == bv && oi < bi)) { bv = ov; bi = oi; }
        }
        if (lane == 0) idx[node] = bi;
    }
}

// ---------------- K_B: scan1 (blocks 0..NB_SCAN) UNION layer-1 transform (rest) ----------------
// Transform writes hT rows and meta.xy = {asrc,adst}. r0/r1 (meta.zw) filled by binB.
template <int FIN, int FOUT>
__global__ void __launch_bounds__(256)
k_scan_tr(const int* __restrict__ vals, int* __restrict__ excl, int* __restrict__ bsums, int M,
          const float* __restrict__ emb, const int* __restrict__ idx,
          const float* __restrict__ W, const float* __restrict__ a_src,
          const float* __restrict__ a_dst, _Float16* __restrict__ hT,
          int4* __restrict__ meta, int N, int NB_SCAN) {
    __shared__ int s[256];
    __shared__ float sW[FIN * FOUT];
    __shared__ float sa[FOUT], sd[FOUT];
    int t = threadIdx.x;
    if ((int)blockIdx.x < NB_SCAN) {
        int i = blockIdx.x * 256 + t;
        int v = (i < M) ? vals[i] : 0;
        s[t] = v;
        __syncthreads();
        for (int off = 1; off < 256; off <<= 1) {
            int a = (t >= off) ? s[t - off] : 0;
            __syncthreads();
            s[t] += a;
            __syncthreads();
        }
        if (i < M) excl[i] = s[t] - v;
        if (t == 255) bsums[blockIdx.x] = s[255];   // raw chunk sums (scanned locally by consumers)
    } else {
        for (int i = t; i < FIN * FOUT; i += 256) sW[i] = W[i];
        if (t < FOUT) { sa[t] = a_src[t]; sd[t] = a_dst[t]; }
        __syncthreads();
        int n = ((int)blockIdx.x - NB_SCAN) * 256 + t;
        if (n >= N) return;
        float acc[FOUT];
#pragma unroll
        for (int f = 0; f < FOUT; f++) acc[f] = 0.f;
        const float* hr = emb + (long long)idx[n] * FIN;
        for (int k = 0; k < FIN; k++) {
            float v = hr[k];
#pragma unroll
            for (int f = 0; f < FOUT; f++) acc[f] += v * sW[k * FOUT + f];
        }
        float s1 = 0.f, s2 = 0.f;
        _Float16 hh[16];
#pragma unroll
        for (int f = 0; f < 16; f++) hh[f] = (_Float16)0.f;
#pragma unroll
        for (int f = 0; f < FOUT; f++) {
            hh[f] = (_Float16)acc[f];
            s1 += acc[f] * sa[f];
            s2 += acc[f] * sd[f];
        }
        uint4* hrow = (uint4*)(hT + (long long)n * 16);
        hrow[0] = ((uint4*)hh)[0];
        hrow[1] = ((uint4*)hh)[1];
        float2 am; am.x = s1; am.y = s2;
        *(float2*)&meta[n] = am;   // xy only; zw written by binB
    }
}

// ---------------- scatB: exact-slot scatter; LDS cursors; local 391-scan of bsums ----------------
template <int B2>
__global__ void __launch_bounds__(1024)
k_scatB(const int* __restrict__ esrc, const int* __restrict__ edst, int E,
        const int* __restrict__ sexcl, const int* __restrict__ bsums,
        int* __restrict__ tmp, int NBUK) {
    __shared__ int cur[NBUK_MAX];
    __shared__ int bex[512];
    int t = threadIdx.x, b = blockIdx.x;
    if (t < 512) bex[t] = (t < NBUK) ? bsums[t] : 0;
    __syncthreads();
    for (int off = 1; off < 512; off <<= 1) {            // inclusive scan, 512 wide
        int a = (t < 512 && t >= off) ? bex[t - off] : 0;
        __syncthreads();
        if (t < 512) bex[t] += a;
        __syncthreads();
    }
    for (int k = t; k < NBUK; k += 1024)
        cur[k] = sexcl[(long long)k * B2 + b] + (k ? bex[k - 1] : 0);
    __syncthreads();
    long long ebeg = (long long)b * E / B2, eend = (long long)(b + 1) * E / B2;
    for (long long i = ebeg + t; i < eend; i += 1024) {
        int d = __builtin_nontemporal_load(&edst[i]);
        int sv = __builtin_nontemporal_load(&esrc[i]);
        int pos = atomicAdd(&cur[d >> 8], 1);
        tmp[pos] = ((d & 255) << 17) | sv;   // src < 2^17; cached store (coalesces in L2)
    }
}

// ---------------- binB: 256-dst buckets; natural-order CSR slots (no sort) ----------------
// 512 threads: edge loops stride 512; scan sections run on low 256 threads.
// Writes {r0,r1} into meta[d].zw.
template <int B2>
__global__ void __launch_bounds__(512)
k_binB(const int* __restrict__ sexcl, const int* __restrict__ bsums,
       const int* __restrict__ tmp, int4* __restrict__ meta,
       int* __restrict__ csr_src, int N, int NBUK, int E) {
    __shared__ int bx[512];
    __shared__ int cnt[256];
    __shared__ int ssc[256];
    __shared__ int cur[256];
    int t = threadIdx.x, b = blockIdx.x;
    bx[t] = (t < NBUK) ? bsums[t] : 0;
    __syncthreads();
    for (int off = 1; off < 512; off <<= 1) {            // inclusive scan, 512 wide
        int a = (t >= off) ? bx[t - off] : 0;
        __syncthreads();
        bx[t] += a;
        __syncthreads();
    }
    int t0 = sexcl[(long long)b * B2] + (b ? bx[b - 1] : 0);
    int t1 = (b + 1 < NBUK) ? (sexcl[(long long)(b + 1) * B2] + bx[b]) : E;
    if (t < 256) cnt[t] = 0;
    __syncthreads();
    for (int i = t0 + t; i < t1; i += 512)
        atomicAdd(&cnt[__builtin_nontemporal_load(&tmp[i]) >> 17], 1);
    __syncthreads();
    int d = b * 256 + t;
    bool valid = (t < 256) && (d < N);
    int dg = (t < 256) ? cnt[t] : 0;      // full degree of dst d

    // exclusive scan of degrees in natural order (low 256 threads)
    if (t < 256) ssc[t] = dg;
    __syncthreads();
    for (int off = 1; off < 256; off <<= 1) {
        int a = (t < 256 && t >= off) ? ssc[t - off] : 0;
        __syncthreads();
        if (t < 256) ssc[t] += a;
        __syncthreads();
    }
    if (valid) {
        int base = t0 + ssc[t] - dg;  // exclusive offset, natural dst order
        cur[t] = base;                // cursor indexed by dst low-bits (scatter key)
        int2 m; m.x = base; m.y = base + dg;
        *(int2*)((char*)&meta[d] + 8) = m;   // meta.zw = {r0, r1}
    }
    __syncthreads();
    for (int i = t0 + t; i < t1; i += 512) {
        int p = __builtin_nontemporal_load(&tmp[i]);
        int pos = atomicAdd(&cur[p >> 17], 1);
        csr_src[pos] = p & 0x1FFFF;   // cached store (coalesces in L2)
    }
}

// ---------------- GAT aggregation core: 4-lane groups; single H gather per edge ----------------
// alpha_src[s] recomputed in-register: dot(h_slice, aw) + 2x shfl_xor(,,4). p is
// group-uniform -> psum needs no final reduce and no p-broadcast shfls.
template <typename EPI>
__device__ __forceinline__ void gat_core4(const _Float16* __restrict__ hT,
                                          v4f aw,                       // lane's 4 a_src weights
                                          const int4* __restrict__ meta,
                                          const int* __restrict__ csr_src,
                                          int d, int l4, EPI epilogue) {
    const char* __restrict__ Hb = (const char*)hT;     // row s at byte s*32; lane slice +l4*8
    int4 m = meta[d];
    float as_d = __int_as_float(m.x);
    float ad   = __int_as_float(m.y);
    int r0 = m.z, r1 = m.w;

    // self loop (exact f32 asrc from meta)
    float e0 = as_d + ad;
    e0 = (e0 >= 0.f) ? e0 : NEG_SLOPE * e0;
    float p0 = __expf(e0);
    h4v hd = *(const h4v*)(Hb + (((unsigned)d) << 5) + (l4 << 3));
    float a0 = p0 * (float)hd[0], a1 = p0 * (float)hd[1];
    float a2 = p0 * (float)hd[2], a3 = p0 * (float)hd[3];
    float psum = p0;                                   // group-uniform accumulation

    int rem = r1 - r0;
    if (rem > 0) {
        int nch = (rem + 3) >> 2;

#define SLOAD(S, c) do { \
        int jj = r0 + ((c) << 2) + l4; \
        int jc = (jj < r1) ? jj : r0; \
        int sr = __builtin_nontemporal_load(&csr_src[jc]); \
        S = (jj < r1) ? sr : d; } while (0)

#define HGATH(S, H0, H1, H2, H3) do { \
        { int sk = __shfl(S, 0, 4); H0 = *(const h4v*)(Hb + (((unsigned)sk) << 5) + (l4 << 3)); } \
        { int sk = __shfl(S, 1, 4); H1 = *(const h4v*)(Hb + (((unsigned)sk) << 5) + (l4 << 3)); } \
        { int sk = __shfl(S, 2, 4); H2 = *(const h4v*)(Hb + (((unsigned)sk) << 5) + (l4 << 3)); } \
        { int sk = __shfl(S, 3, 4); H3 = *(const h4v*)(Hb + (((unsigned)sk) << 5) + (l4 << 3)); } } while (0)

#define PEDGE(Hk, kk, c) do { \
        float f0 = (float)Hk[0], f1 = (float)Hk[1], f2 = (float)Hk[2], f3 = (float)Hk[3]; \
        float dt = f0 * aw.x + f1 * aw.y + f2 * aw.z + f3 * aw.w; \
        dt += __shfl_xor(dt, 1, 4); \
        dt += __shfl_xor(dt, 2, 4); \
        float e = dt + ad; \
        e = (e >= 0.f) ? e : NEG_SLOPE * e; \
        float p = (r0 + ((c) << 2) + (kk) < r1) ? __expf(e) : 0.f; \
        psum += p; \
        a0 += p * f0; a1 += p * f1; a2 += p * f2; a3 += p * f3; } while (0)

#define PROC(H0, H1, H2, H3, c) do { \
        PEDGE(H0, 0, c); PEDGE(H1, 1, c); PEDGE(H2, 2, c); PEDGE(H3, 3, c); } while (0)

        int sA, sB = d, sC = d;
        h4v hA0, hA1, hA2, hA3, hB0, hB1, hB2, hB3;

        SLOAD(sA, 0);
        HGATH(sA, hA0, hA1, hA2, hA3);
        if (nch > 1) SLOAD(sB, 1);
        int c = 0;
        while (c + 1 < nch) {
            if (c + 2 < nch) SLOAD(sC, c + 2);
            HGATH(sB, hB0, hB1, hB2, hB3);     // issue next chunk's gathers
            PROC(hA0, hA1, hA2, hA3, c);       // consume current chunk
            hA0 = hB0; hA1 = hB1; hA2 = hB2; hA3 = hB3;
            sB = sC;
            c++;
        }
        PROC(hA0, hA1, hA2, hA3, c);
#undef SLOAD
#undef HGATH
#undef PEDGE
#undef PROC
    }
    float inv = 1.f / fmaxf(psum, 1e-16f);
    epilogue(d, r0, r1, a0 * inv, a1 * inv, a2 * inv, a3 * inv);
}

// gat + bias/relu + NEXT-layer transform fused; writes next-layer hT/meta
template <int FN>
__global__ void __launch_bounds__(256)
k_gat_ft(const _Float16* __restrict__ hT, const int4* __restrict__ meta,
         const int* __restrict__ csr_src,
         const float* __restrict__ a_cur,       // current-layer a_src (16 entries)
         const float* __restrict__ bias,
         const float* __restrict__ Wn, const float* __restrict__ an_src,
         const float* __restrict__ an_dst,
         _Float16* __restrict__ hT_n, int4* __restrict__ meta_n, int N) {
    __shared__ float sW[16 * 16];
    __shared__ float sa[16], sd[16], sb[16];
    int t = threadIdx.x;
    {
        int k = t >> 4, f = t & 15;
        sW[t] = (f < FN) ? Wn[k * FN + f] : 0.f;
    }
    if (t < 16) {
        sa[t] = (t < FN) ? an_src[t] : 0.f;
        sd[t] = (t < FN) ? an_dst[t] : 0.f;
        sb[t] = bias[t];
    }
    __syncthreads();

    int gid = blockIdx.x * 256 + t;
    int d = gid >> 2, l4 = gid & 3;    // sequential dsts: meta/self/out coalesce per wave
    if (d >= N) return;
    int fb = l4 << 2;
    v4f aw = { a_cur[fb], a_cur[fb + 1], a_cur[fb + 2], a_cur[fb + 3] };

    gat_core4(hT, aw, meta, csr_src, d, l4,
        [&](int dd, int r0, int r1, float v0, float v1, float v2, float v3) {
            int f0 = l4 * 4;
            float vv[4];
            vv[0] = fmaxf(v0 + sb[f0    ], 0.f);
            vv[1] = fmaxf(v1 + sb[f0 + 1], 0.f);
            vv[2] = fmaxf(v2 + sb[f0 + 2], 0.f);
            vv[3] = fmaxf(v3 + sb[f0 + 3], 0.f);
            float o0 = 0.f, o1 = 0.f, o2 = 0.f, o3 = 0.f;
#pragma unroll
            for (int q = 0; q < 4; q++) {
#pragma unroll
                for (int i = 0; i < 4; i++) {
                    float vk = __shfl(vv[i], q, 4);      // broadcast feature k=q*4+i of dst
                    const float* wr = &sW[(q * 4 + i) * 16 + f0];
                    o0 += vk * wr[0];
                    o1 += vk * wr[1];
                    o2 += vk * wr[2];
                    o3 += vk * wr[3];
                }
            }
            float c1 = o0 * sa[f0] + o1 * sa[f0 + 1] + o2 * sa[f0 + 2] + o3 * sa[f0 + 3];
            float c2 = o0 * sd[f0] + o1 * sd[f0 + 1] + o2 * sd[f0 + 2] + o3 * sd[f0 + 3];
            c1 += __shfl_xor(c1, 1, 4); c1 += __shfl_xor(c1, 2, 4);
            c2 += __shfl_xor(c2, 1, 4); c2 += __shfl_xor(c2, 2, 4);
            h4v ho = { (_Float16)o0, (_Float16)o1, (_Float16)o2, (_Float16)o3 };
            ((h4v*)hT_n)[(long long)dd * 4 + l4] = ho;
            if (l4 == 0) {
                int4 mm;
                mm.x = __float_as_int(c1); mm.y = __float_as_int(c2);
                mm.z = r0; mm.w = r1;
                meta_n[dd] = mm;
            }
        });
}

// final gat: fp32 out rows padded to stride 16 (cols >=10 are zero); FC = current a_src len
template <int FC>
__global__ void __launch_bounds__(256)
k_gat_last(const _Float16* __restrict__ hT, const int4* __restrict__ meta,
           const int* __restrict__ csr_src,
           const float* __restrict__ a_cur, float* __restrict__ out, int N) {
    int gid = blockIdx.x * 256 + threadIdx.x;
    int d = gid >> 2, l4 = gid & 3;
    if (d >= N) return;
    int fb = l4 << 2;
    v4f aw;
    aw.x = (fb     < FC) ? a_cur[fb]     : 0.f;
    aw.y = (fb + 1 < FC) ? a_cur[fb + 1] : 0.f;
    aw.z = (fb + 2 < FC) ? a_cur[fb + 2] : 0.f;
    aw.w = (fb + 3 < FC) ? a_cur[fb + 3] : 0.f;
    gat_core4(hT, aw, meta, csr_src, d, l4,
        [&](int dd, int r0, int r1, float v0, float v1, float v2, float v3) {
            v4f o = { v0, v1, v2, v3 };
            ((v4f*)out)[(long long)dd * 4 + l4] = o;
        });
}

// ---------------- pool + softmax (h3 rows have stride 16) ----------------
__global__ void k_pool(const float* __restrict__ h3, const int* __restrict__ batch,
                       const float* __restrict__ b3, float* __restrict__ out, int N, int C) {
    int g = blockIdx.x;
    int lo = 0, hi = N;
    while (lo < hi) { int mid = (lo + hi) >> 1; if (batch[mid] < g) lo = mid + 1; else hi = mid; }
    int start = lo;
    hi = N;
    while (lo < hi) { int mid = (lo + hi) >> 1; if (batch[mid] < g + 1) lo = mid + 1; else hi = mid; }
    int end = lo;

    float sum[16];
    for (int f = 0; f < C; f++) sum[f] = 0.f;
    for (int n = start + threadIdx.x; n < end; n += blockDim.x) {
        const float* r = h3 + (long long)n * 16;
        for (int f = 0; f < C; f++) sum[f] += r[f];
    }
    __shared__ float red[256 * 16];
    for (int f = 0; f < C; f++) red[threadIdx.x * 16 + f] = sum[f];
    __syncthreads();
    for (int str = blockDim.x / 2; str > 0; str >>= 1) {
        if ((int)threadIdx.x < str)
            for (int f = 0; f < C; f++) red[threadIdx.x * 16 + f] += red[(threadIdx.x + str) * 16 + f];
        __syncthreads();
    }
    if (threadIdx.x == 0) {
        float cnt = fmaxf((float)(end - start), 1.f);
        float vals[16];
        float mx = -INFINITY;
        for (int f = 0; f < C; f++) { vals[f] = red[f] / cnt + b3[f]; mx = fmaxf(mx, vals[f]); }
        float se = 0.f;
        for (int f = 0; f < C; f++) { vals[f] = __expf(vals[f] - mx); se += vals[f]; }
        for (int f = 0; f < C; f++) out[(long long)g * C + f] = vals[f] / se;
    }
}

extern "C" void kernel_launch(void* const* d_in, const int* in_sizes, int n_in,
                              void* d_out, int out_size, void* d_ws, size_t ws_size,
                              hipStream_t stream) {
    const float* x    = (const float*)d_in[0];
    const int*   eidx = (const int*)d_in[1];
    const int*   batch= (const int*)d_in[2];
    const float* emb  = (const float*)d_in[3];
    const float* W1   = (const float*)d_in[4];
    const float* as1  = (const float*)d_in[5];
    const float* ad1  = (const float*)d_in[6];
    const float* b1   = (const float*)d_in[7];
    const float* W2   = (const float*)d_in[8];
    const float* as2  = (const float*)d_in[9];
    const float* ad2  = (const float*)d_in[10];
    const float* b2   = (const float*)d_in[11];
    const float* W3   = (const float*)d_in[12];
    const float* as3  = (const float*)d_in[13];
    const float* ad3  = (const float*)d_in[14];
    const float* b3   = (const float*)d_in[15];

    const int H = in_sizes[5];          // 16
    const int C = in_sizes[13];         // 10
    const int D = in_sizes[4] / H;      // 50
    const int V = in_sizes[3] / D;      // 128
    const int N = in_sizes[0] / V;      // 100000
    const int E = in_sizes[1] / 2;      // 1600000
    const int G = out_size / C;         // 512
    const int* esrc = eidx;
    const int* edst = eidx + E;
    const int NBUK = (N + 255) >> 8;    // 391 buckets of 256 dsts (must be <=512)
    constexpr int B2 = 256;             // scatter blocks; bucket runs ~16 entries = one 64B line
    const int M = NBUK * B2;            // histT elements (100K)

    char* w = (char*)d_ws;
    auto carve = [&](size_t bytes) {
        char* p = w;
        w += (bytes + 255) & ~(size_t)255;
        return p;
    };
    int*      idx     = (int*)carve((size_t)N * 4);
    int*      histT   = (int*)carve((size_t)M * 4);
    int*      sexcl   = (int*)carve((size_t)M * 4);
    int*      bsums   = (int*)carve(2048 * 4);
    int*      csr_src = (int*)carve((size_t)E * 4);
    _Float16* hTa     = (_Float16*)carve((size_t)N * 32);
    _Float16* hTb     = (_Float16*)carve((size_t)N * 32);
    int4*     metaA   = (int4*)carve((size_t)N * 16);
    int4*     metaB   = (int4*)carve((size_t)N * 16);
    size_t zone_bytes = ((size_t)E * 4 > (size_t)N * 64) ? (size_t)E * 4 : (size_t)N * 64;
    char*  zone = carve(zone_bytes);
    float* X0  = (float*)zone;          // N x 16 fp32 padded rows (after tmp is dead)
    int*   tmp = (int*)zone;
    (void)ws_size; (void)n_in;

    const int BT = 256;
    dim3 blk(BT);
    int gGat4 = (N * 4 + BT - 1) / BT;      // 4 lanes per dst
    int nb2   = (M + 255) / 256;            // scan blocks over histT (= NBUK = 391)
    int gArg  = (N + 31) / 32;              // argmax blocks (32 nodes per 1024-thr block)
    int gTr   = (N + BT - 1) / BT;          // transform blocks

    // ---- K_A: histB (LDS bucket hist) + argmax in one launch ----
    k_histarg<B2><<<B2 + gArg, dim3(1024), 0, stream>>>(x, edst, E, histT, NBUK, idx, N, V);

    // ---- K_B: scan1 + layer-1 transform in one launch (bsums stay raw chunk sums) ----
    k_scan_tr<50, 16><<<nb2 + gTr, blk, 0, stream>>>(histT, sexcl, bsums, M,
                                                     emb, idx, W1, as1, ad1,
                                                     hTa, metaA, N, nb2);

    // ---- scatter to bucket-ordered tmp, then bin to natural-order CSR slots ----
    k_scatB<B2><<<B2, dim3(1024), 0, stream>>>(esrc, edst, E, sexcl, bsums, tmp, NBUK);
    k_binB<B2><<<NBUK, dim3(512), 0, stream>>>(sexcl, bsums, tmp, metaA, csr_src, N, NBUK, E);

    // ---- gat1 (+b1,relu) fused with transform2 -> hTb/metaB ----
    k_gat_ft<16><<<gGat4, blk, 0, stream>>>(hTa, metaA, csr_src, as1, b1,
                                            W2, as2, ad2, hTb, metaB, N);

    // ---- gat2 (+b2,relu) fused with transform3 -> hTa/metaA ----
    k_gat_ft<10><<<gGat4, blk, 0, stream>>>(hTb, metaB, csr_src, as2, b2,
                                            W3, as3, ad3, hTa, metaA, N);

    // ---- gat3 -> X0 (N x 16 fp32, cols >=10 zero) ----
    k_gat_last<10><<<gGat4, blk, 0, stream>>>(hTa, metaA, csr_src, as3, X0, N);

    // ---- pool + softmax ----
    k_pool<<<G, blk, 0, stream>>>(X0, batch, b3, (float*)d_out, N, C);
}